// Round 6
// baseline (1182.491 us; speedup 1.0000x reference)
//
#include <hip/hip_runtime.h>
#include <hip/hip_bf16.h>
#include <math.h>

using bf16 = __hip_bfloat16;

typedef short s16x8 __attribute__((ext_vector_type(8)));
typedef float f32x4 __attribute__((ext_vector_type(4)));

// Problem dims (fixed by setup_inputs)
constexpr int Bc = 8, Tc = 1024, Dc = 1024, Hc = 8;
constexpr int NTc = 77, LTc = 768, KRc = 1024, Nc = 2125, Ec = 2048;
constexpr float NEGC = -1000000.0f;

// ---- Workspace layout (same total footprint as passing R5 run) ----
constexpr long F_STATS1 = 0;                    // 16,384
constexpr long F_STATS2 = F_STATS1 + 16384;     // 16,384
constexpr long F_KEYADD = F_STATS2 + 16384;     // 17,000
constexpr long F_VALMUL = F_KEYADD + 17000;     // 17,000
constexpr long F_SILU   = F_VALMUL + 17000;     // 16,384 (cs_m[8192] + cs_inv[8192])
constexpr long F_EO     = F_SILU + 16384;       // 16,384
constexpr long F_ATT    = F_EO + 16384;         // 1,048,576 (atomic accumulation target)
constexpr long F_END    = F_ATT + 1048576;
// bf16 region. NOTE ordering: WQ|WKM|WVM contiguous -> one [3072][1024] B^T;
// WKT|WVT contiguous -> one [2048][768] B^T.
constexpr long B_NORMX = 0;                     // 8,388,608 (reused: y16)
constexpr long B_Q     = B_NORMX + 8388608;     // 8,388,608 (reused: s16)
constexpr long B_KEY   = B_Q + 8388608;         // 17,408,000
constexpr long B_V     = B_KEY + 17408000;      // 17,408,000 (reused: eo_part fp32)
constexpr long B_NXF   = B_V + 17408000;        // 473,088
constexpr long B_WQ    = B_NXF + 473088;        // 1,048,576
constexpr long B_WKM   = B_WQ + 1048576;        // 1,048,576
constexpr long B_WVM   = B_WKM + 1048576;       // 1,048,576
constexpr long B_WKT   = B_WVM + 1048576;       // 786,432
constexpr long B_WVT   = B_WKT + 786432;        // 786,432
constexpr long B_WKR   = B_WVT + 786432;        // 2,097,152 (reused: ksm part_m/part_s)
constexpr long B_WVR   = B_WKR + 2097152;       // 1,048,576
constexpr long B_WO    = B_WVR + 1048576;       // 1,048,576
constexpr long B_END   = B_WO + 1048576;
constexpr size_t WS_NEED = (size_t)F_END * 4 + (size_t)B_END * 2;

__device__ __forceinline__ float b2f(bf16 v) { return __bfloat162float(v); }
__device__ __forceinline__ bf16 f2b(float v) { return __float2bfloat16(v); }
__device__ __forceinline__ short f2s(float v) {
    bf16 h = __float2bfloat16(v);
    return *reinterpret_cast<short*>(&h);
}
__device__ __forceinline__ float us2f(unsigned short u) {
    bf16 h = *reinterpret_cast<bf16*>(&u);
    return __bfloat162float(h);
}
__device__ __forceinline__ void storef(float* p, float v) { *p = v; }
__device__ __forceinline__ void storef(bf16* p, float v) { *p = __float2bfloat16(v); }

// async global->LDS, 16B per lane. LDS dest must be wave-uniform base + lane*16.
typedef __attribute__((address_space(1))) const unsigned int gu32;
typedef __attribute__((address_space(3))) unsigned int lu32;
__device__ __forceinline__ void gl_lds16(const void* g, void* l) {
    __builtin_amdgcn_global_load_lds((gu32*)g, (lu32*)l, 16, 0, 0);
}

__device__ __forceinline__ float2 block_sum2(float s, float s2) {
    #pragma unroll
    for (int off = 32; off > 0; off >>= 1) {
        s  += __shfl_down(s, off, 64);
        s2 += __shfl_down(s2, off, 64);
    }
    __shared__ float sh[4], sh2[4];
    int w = threadIdx.x >> 6, lane = threadIdx.x & 63;
    if (lane == 0) { sh[w] = s; sh2[w] = s2; }
    __syncthreads();
    s = sh[0] + sh[1] + sh[2] + sh[3];
    s2 = sh2[0] + sh2[1] + sh2[2] + sh2[3];
    return make_float2(s, s2);
}

// Row LayerNorm: one block (256 thr) per row
template <typename TO>
__global__ __launch_bounds__(256) void ln_rows(const float* __restrict__ in,
                                               const float* __restrict__ g,
                                               const float* __restrict__ b,
                                               TO* __restrict__ out, int C) {
    long row = blockIdx.x;
    const float* x = in + row * (long)C;
    TO* o = out + row * (long)C;
    float s = 0.f, s2 = 0.f;
    for (int c = threadIdx.x; c < C; c += 256) { float v = x[c]; s += v; s2 += v * v; }
    float2 r = block_sum2(s, s2);
    float mean = r.x / C;
    float var = r.y / C - mean * mean;
    float inv = rsqrtf(var + 1e-5f);
    for (int c = threadIdx.x; c < C; c += 256)
        storef(&o[c], (x[c] - mean) * inv * g[c] + b[c]);
}

// Both retrieval LN stats in one pass over re_motion
__global__ __launch_bounds__(256) void ln_stats_both(const float* __restrict__ motion,
                                                     const float* __restrict__ text,
                                                     float* __restrict__ stats1,
                                                     float* __restrict__ stats2) {
    long row = blockIdx.x;  // b*1024 + k*512 + r
    const float* m = motion + row * 1024;
    const float* tx = text + (row >> 9) * 1024;
    float s = 0.f, s2 = 0.f;
    for (int c = threadIdx.x; c < 1024; c += 256) { float v = m[c]; s += v; s2 += v * v; }
    float2 rm = block_sum2(s, s2);
    __syncthreads();
    float st = 0.f, st2 = 0.f;
    for (int c = threadIdx.x; c < 1024; c += 256) { float v = tx[c]; st += v; st2 += v * v; }
    float2 rt = block_sum2(st, st2);
    if (threadIdx.x == 0) {
        float mean2 = rm.x / 1024.f;
        float var2 = rm.y / 1024.f - mean2 * mean2;
        stats2[2 * row] = mean2;
        stats2[2 * row + 1] = rsqrtf(var2 + 1e-5f);
        float mean1 = (rm.x + rt.x) / 2048.f;
        float var1 = (rm.y + rt.y) / 2048.f - mean1 * mean1;
        stats1[2 * row] = mean1;
        stats1[2 * row + 1] = rsqrtf(var1 + 1e-5f);
    }
}

// Per-(b, n) key additive mask and value multiplicative mask
__global__ __launch_bounds__(256) void prep_masks(const int* __restrict__ cond_type,
                                                  const float* __restrict__ src_mask,
                                                  const float* __restrict__ re_mask,
                                                  float* __restrict__ key_add,
                                                  float* __restrict__ val_mul) {
    int idx = blockIdx.x * 256 + threadIdx.x;
    if (idx >= Bc * Nc) return;
    int b = idx / Nc, n = idx % Nc;
    int ct = cond_type[b];
    float text_ct = ((ct % 10) > 0) ? 1.f : 0.f;
    float retr_ct = ((ct / 10) > 0) ? 1.f : 0.f;
    float add, mul;
    if (n < NTc) {
        add = (1.f - text_ct) * NEGC; mul = text_ct;
    } else if (n < NTc + KRc) {
        float rm = re_mask[b * KRc + (n - NTc)];
        add = (1.f - retr_ct) * NEGC + (1.f - rm) * NEGC;
        mul = retr_ct * rm;
    } else {
        float sm = src_mask[b * Tc + (n - NTc - KRc)];
        add = (1.f - sm) * NEGC; mul = sm;
    }
    key_add[idx] = add;
    val_mul[idx] = mul;
}

// Transpose + convert weight: W[K][N] fp32 -> Wt[N][K] bf16(short)
__global__ __launch_bounds__(256) void transpose_w(const float* __restrict__ W,
                                                   short* __restrict__ Wt,
                                                   int K, int N) {
    __shared__ float t[32][33];
    int n0 = blockIdx.x * 32, k0 = blockIdx.y * 32;
    int tx = threadIdx.x & 31, ty = threadIdx.x >> 5;
    #pragma unroll
    for (int i = 0; i < 4; ++i)
        t[ty + i * 8][tx] = W[(long)(k0 + ty + i * 8) * N + n0 + tx];
    __syncthreads();
    #pragma unroll
    for (int i = 0; i < 4; ++i)
        Wt[(long)(n0 + ty + i * 8) * K + k0 + tx] = f2s(t[tx][ty + i * 8]);
}

// ======================= MFMA GEMM (B^T layout, async LDS staging) ==========
constexpr int LDK = 64;

template <typename TC>
__global__ __launch_bounds__(256) void gemm_bt(
    const short* __restrict__ A, int lda, long sA,
    const short* __restrict__ Bt, int ldb,
    const float* __restrict__ bias,
    const float* __restrict__ addC, int ldac, long sAC,
    TC* __restrict__ C, int ldc, long sC,
    int M, int K) {
    int bz = blockIdx.z;
    A += (long)bz * sA;
    C += (long)bz * sC;
    if (addC) addC += (long)bz * sAC;

    const int tm = blockIdx.y * 128;
    const int tn = blockIdx.x * 128;

    __shared__ __align__(16) short As[128 * LDK];
    __shared__ __align__(16) short Bs[128 * LDK];

    int tid = threadIdx.x;
    int lane = tid & 63, wid = tid >> 6;
    int wi = wid >> 1, wj = wid & 1;
    int l16 = lane & 15, quad = lane >> 4;

    f32x4 acc[4][4];
    #pragma unroll
    for (int i = 0; i < 4; ++i)
        #pragma unroll
        for (int j = 0; j < 4; ++j)
            acc[i][j] = (f32x4){0.f, 0.f, 0.f, 0.f};

    auto issue = [&](int k0) {
        #pragma unroll
        for (int p = 0; p < 4; ++p) {
            int e = p * 256 + tid;
            int row = e >> 3, c8 = e & 7;
            int gm = tm + row;
            if (gm >= M) gm = M - 1;
            gl_lds16(A + (long)gm * lda + k0 + c8 * 8, &As[row * LDK + c8 * 8]);
            gl_lds16(Bt + (long)(tn + row) * ldb + k0 + c8 * 8, &Bs[row * LDK + c8 * 8]);
        }
    };

    issue(0);
    int kt = 0;
    while (true) {
        __syncthreads();
        #pragma unroll
        for (int kk = 0; kk < 2; ++kk) {
            s16x8 af[4], bfr[4];
            #pragma unroll
            for (int i = 0; i < 4; ++i)
                af[i] = *(const s16x8*)&As[(wi * 64 + i * 16 + l16) * LDK + kk * 32 + quad * 8];
            #pragma unroll
            for (int j = 0; j < 4; ++j)
                bfr[j] = *(const s16x8*)&Bs[(wj * 64 + j * 16 + l16) * LDK + kk * 32 + quad * 8];
            #pragma unroll
            for (int i = 0; i < 4; ++i)
                #pragma unroll
                for (int j = 0; j < 4; ++j)
                    acc[i][j] = __builtin_amdgcn_mfma_f32_16x16x32_bf16(af[i], bfr[j], acc[i][j], 0, 0, 0);
        }
        int nxt = kt + 64;
        if (nxt >= K) break;
        __syncthreads();
        issue(nxt);
        kt = nxt;
    }

    #pragma unroll
    for (int i = 0; i < 4; ++i) {
        #pragma unroll
        for (int r = 0; r < 4; ++r) {
            int gm = tm + wi * 64 + i * 16 + quad * 4 + r;
            if (gm >= M) continue;
            #pragma unroll
            for (int j = 0; j < 4; ++j) {
                int gn = tn + wj * 64 + j * 16 + l16;
                float v = acc[i][j][r] + (bias ? bias[gn] : 0.f);
                if (addC) v += addC[(long)gm * ldac + gn];
                storef(&C[(long)gm * ldc + gn], v);
            }
        }
    }
}

// Fused QKV / KV GEMM: B^T is a vertical concat of up to 3 weight blocks.
// Tiles [0,qT) -> Q (bias only); [qT, qT+8) -> K (+bias +rowadd);
// [qT+8, qT+16) -> V ((+bias) * rowmul).  All outputs N=1024, ldc=Dc.
__global__ __launch_bounds__(256) void gemm_bt_qkv(
    const short* __restrict__ A, int lda, long sA,
    const short* __restrict__ Bt, int ldb,
    const float* __restrict__ biasQ,
    const float* __restrict__ biasK,
    const float* __restrict__ biasV,
    const float* __restrict__ rowadd,   // base (pre-offset); +bz*Nc inside
    const float* __restrict__ rowmul,
    bf16* __restrict__ Cq, long sCq,
    bf16* __restrict__ Ck, long sCk,
    bf16* __restrict__ Cv, long sCv,
    int qT, int M, int K) {
    int bz = blockIdx.z;
    A += (long)bz * sA;
    rowadd += (long)bz * Nc;
    rowmul += (long)bz * Nc;

    int t = blockIdx.x;
    int mode = (t < qT) ? 0 : (t < qT + 8 ? 1 : 2);
    const int tm = blockIdx.y * 128;
    const int tn = t * 128;  // row base into concatenated Bt
    int cn = tn - (mode == 0 ? 0 : (mode == 1 ? qT * 128 : (qT + 8) * 128));

    __shared__ __align__(16) short As[128 * LDK];
    __shared__ __align__(16) short Bs[128 * LDK];

    int tid = threadIdx.x;
    int lane = tid & 63, wid = tid >> 6;
    int wi = wid >> 1, wj = wid & 1;
    int l16 = lane & 15, quad = lane >> 4;

    f32x4 acc[4][4];
    #pragma unroll
    for (int i = 0; i < 4; ++i)
        #pragma unroll
        for (int j = 0; j < 4; ++j)
            acc[i][j] = (f32x4){0.f, 0.f, 0.f, 0.f};

    auto issue = [&](int k0) {
        #pragma unroll
        for (int p = 0; p < 4; ++p) {
            int e = p * 256 + tid;
            int row = e >> 3, c8 = e & 7;
            int gm = tm + row;
            if (gm >= M) gm = M - 1;
            gl_lds16(A + (long)gm * lda + k0 + c8 * 8, &As[row * LDK + c8 * 8]);
            gl_lds16(Bt + (long)(tn + row) * ldb + k0 + c8 * 8, &Bs[row * LDK + c8 * 8]);
        }
    };

    issue(0);
    int kt = 0;
    while (true) {
        __syncthreads();
        #pragma unroll
        for (int kk = 0; kk < 2; ++kk) {
            s16x8 af[4], bfr[4];
            #pragma unroll
            for (int i = 0; i < 4; ++i)
                af[i] = *(const s16x8*)&As[(wi * 64 + i * 16 + l16) * LDK + kk * 32 + quad * 8];
            #pragma unroll
            for (int j = 0; j < 4; ++j)
                bfr[j] = *(const s16x8*)&Bs[(wj * 64 + j * 16 + l16) * LDK + kk * 32 + quad * 8];
            #pragma unroll
            for (int i = 0; i < 4; ++i)
                #pragma unroll
                for (int j = 0; j < 4; ++j)
                    acc[i][j] = __builtin_amdgcn_mfma_f32_16x16x32_bf16(af[i], bfr[j], acc[i][j], 0, 0, 0);
        }
        int nxt = kt + 64;
        if (nxt >= K) break;
        __syncthreads();
        issue(nxt);
        kt = nxt;
    }

    #pragma unroll
    for (int i = 0; i < 4; ++i) {
        #pragma unroll
        for (int r = 0; r < 4; ++r) {
            int gm = tm + wi * 64 + i * 16 + quad * 4 + r;
            if (gm >= M) continue;
            #pragma unroll
            for (int j = 0; j < 4; ++j) {
                int col = cn + wj * 64 + j * 16 + l16;
                float v = acc[i][j][r];
                if (mode == 0) {
                    v += biasQ[col];
                    Cq[(long)bz * sCq + (long)gm * Dc + col] = f2b(v);
                } else if (mode == 1) {
                    v += biasK[col] + rowadd[gm];
                    Ck[(long)bz * sCk + (long)gm * Dc + col] = f2b(v);
                } else {
                    v = (v + biasV[col]) * rowmul[gm];
                    Cv[(long)bz * sCv + (long)gm * Dc + col] = f2b(v);
                }
            }
        }
    }
}

// MFMA GEMM with LayerNorm fused into A staging (A via regs->LDS, B async).
template <typename TC>
__global__ __launch_bounds__(256) void gemm_lnA_mfma(
    const float* __restrict__ motion, const float* __restrict__ text,
    const float* __restrict__ stats,
    const float* __restrict__ g, const float* __restrict__ bvec,
    const short* __restrict__ Bt, int ldb,
    const float* __restrict__ bias,
    const float* __restrict__ rowadd, int sRA,
    const float* __restrict__ rowmul, int sRM,
    TC* __restrict__ C, int ldc, long sC,
    int K) {
    int bz = blockIdx.z;
    C += (long)bz * sC;
    if (rowadd) rowadd += (long)bz * sRA;
    if (rowmul) rowmul += (long)bz * sRM;

    const int tm = blockIdx.y * 128;
    const int tn = blockIdx.x * 128;

    __shared__ __align__(16) short As[128 * LDK];
    __shared__ __align__(16) short Bs[128 * LDK];

    int tid = threadIdx.x;
    int lane = tid & 63, wid = tid >> 6;
    int wi = wid >> 1, wj = wid & 1;
    int l16 = lane & 15, quad = lane >> 4;

    f32x4 acc[4][4];
    #pragma unroll
    for (int i = 0; i < 4; ++i)
        #pragma unroll
        for (int j = 0; j < 4; ++j)
            acc[i][j] = (f32x4){0.f, 0.f, 0.f, 0.f};

    uint4 pa[4];

    auto computeA = [&](int k0) {
        #pragma unroll
        for (int p = 0; p < 4; ++p) {
            int e = p * 256 + tid;
            int row = e >> 3, c8 = e & 7;
            long rg = (long)bz * 1024 + tm + row;
            int c = k0 + c8 * 8;
            const float* src = (c < 1024) ? motion + rg * 1024 + c
                                          : text + (rg >> 9) * 1024 + (c - 1024);
            float4 v0 = *(const float4*)src;
            float4 v1 = *(const float4*)(src + 4);
            float mean = stats[2 * rg], rstd = stats[2 * rg + 1];
            float4 g0 = *(const float4*)&g[c], g1 = *(const float4*)&g[c + 4];
            float4 b0 = *(const float4*)&bvec[c], b1 = *(const float4*)&bvec[c + 4];
            union { short s[8]; uint4 u; } pk;
            pk.s[0] = f2s((v0.x - mean) * rstd * g0.x + b0.x);
            pk.s[1] = f2s((v0.y - mean) * rstd * g0.y + b0.y);
            pk.s[2] = f2s((v0.z - mean) * rstd * g0.z + b0.z);
            pk.s[3] = f2s((v0.w - mean) * rstd * g0.w + b0.w);
            pk.s[4] = f2s((v1.x - mean) * rstd * g1.x + b1.x);
            pk.s[5] = f2s((v1.y - mean) * rstd * g1.y + b1.y);
            pk.s[6] = f2s((v1.z - mean) * rstd * g1.z + b1.z);
            pk.s[7] = f2s((v1.w - mean) * rstd * g1.w + b1.w);
            pa[p] = pk.u;
        }
    };
    auto issueB = [&](int k0) {
        #pragma unroll
        for (int p = 0; p < 4; ++p) {
            int e = p * 256 + tid;
            int row = e >> 3, c8 = e & 7;
            gl_lds16(Bt + (long)(tn + row) * ldb + k0 + c8 * 8, &Bs[row * LDK + c8 * 8]);
        }
    };
    auto storeA = [&]() {
        #pragma unroll
        for (int p = 0; p < 4; ++p) {
            int e = p * 256 + tid;
            int row = e >> 3, c8 = e & 7;
            *(uint4*)&As[row * LDK + c8 * 8] = pa[p];
        }
    };

    issueB(0);
    computeA(0);
    storeA();
    int kt = 0;
    while (true) {
        __syncthreads();
        #pragma unroll
        for (int kk = 0; kk < 2; ++kk) {
            s16x8 af[4], bfr[4];
            #pragma unroll
            for (int i = 0; i < 4; ++i)
                af[i] = *(const s16x8*)&As[(wi * 64 + i * 16 + l16) * LDK + kk * 32 + quad * 8];
            #pragma unroll
            for (int j = 0; j < 4; ++j)
                bfr[j] = *(const s16x8*)&Bs[(wj * 64 + j * 16 + l16) * LDK + kk * 32 + quad * 8];
            #pragma unroll
            for (int i = 0; i < 4; ++i)
                #pragma unroll
                for (int j = 0; j < 4; ++j)
                    acc[i][j] = __builtin_amdgcn_mfma_f32_16x16x32_bf16(af[i], bfr[j], acc[i][j], 0, 0, 0);
        }
        int nxt = kt + 64;
        if (nxt >= K) break;
        computeA(nxt);
        __syncthreads();
        issueB(nxt);
        storeA();
        kt = nxt;
    }

    #pragma unroll
    for (int i = 0; i < 4; ++i) {
        #pragma unroll
        for (int r = 0; r < 4; ++r) {
            int gm = tm + wi * 64 + i * 16 + quad * 4 + r;
            float ra = rowadd ? rowadd[gm] : 0.f;
            float rm = rowmul ? rowmul[gm] : 1.f;
            #pragma unroll
            for (int j = 0; j < 4; ++j) {
                int gn = tn + wj * 64 + j * 16 + l16;
                float v = acc[i][j][r] + (bias ? bias[gn] : 0.f) + ra;
                v *= rm;
                storef(&C[(long)gm * ldc + gn], v);
            }
        }
    }
}

// eo split-K
__global__ __launch_bounds__(256) void eo_partial(const float* __restrict__ emb,
                                                  const float* __restrict__ We,
                                                  float* __restrict__ part) {
    int nb = blockIdx.x;
    int ks = blockIdx.y;
    int n = nb * 256 + threadIdx.x;
    int k0 = ks * 64;
    __shared__ float a_s[8][64];
    for (int idx = threadIdx.x; idx < 512; idx += 256) {
        int b = idx >> 6, kk = idx & 63;
        float v = emb[b * 2048 + k0 + kk];
        a_s[b][kk] = v / (1.f + expf(-v));
    }
    __syncthreads();
    float acc[8] = {};
    for (int kk = 0; kk < 64; ++kk) {
        float w = We[(long)(k0 + kk) * 2048 + n];
        #pragma unroll
        for (int b = 0; b < 8; ++b) acc[b] = fmaf(a_s[b][kk], w, acc[b]);
    }
    #pragma unroll
    for (int b = 0; b < 8; ++b) part[((long)ks * 8 + b) * 2048 + n] = acc[b];
}

__global__ __launch_bounds__(256) void eo_reduce(const float* __restrict__ part,
                                                 const float* __restrict__ be,
                                                 float* __restrict__ eo) {
    int idx = blockIdx.x * 256 + threadIdx.x;
    int n = idx & 2047, b = idx >> 11;
    float s = be[n];
    #pragma unroll 8
    for (int ks = 0; ks < 32; ++ks) s += part[((long)ks * 8 + b) * 2048 + n];
    eo[idx] = s;
}

// q softmax over head dim (128): one wave per row, 2 elems/lane.
__global__ __launch_bounds__(256) void softmax_head(bf16* __restrict__ q) {
    long row = (long)blockIdx.x * 4 + (threadIdx.x >> 6);
    int lane = threadIdx.x & 63;
    bf16* p = q + row * 128 + lane * 2;
    float v0 = b2f(p[0]), v1 = b2f(p[1]);
    float mx = fmaxf(v0, v1);
    #pragma unroll
    for (int off = 32; off > 0; off >>= 1) mx = fmaxf(mx, __shfl_xor(mx, off, 64));
    float e0 = expf(v0 - mx), e1 = expf(v1 - mx);
    float s = e0 + e1;
    #pragma unroll
    for (int off = 32; off > 0; off >>= 1) s += __shfl_xor(s, off, 64);
    float inv = 1.f / s;
    p[0] = f2b(e0 * inv);
    p[1] = f2b(e1 * inv);
}

// key-softmax pass 1: per-(split,b) online (max,sumexp) per column
constexpr int KSM_NS = 32;
__global__ __launch_bounds__(256) void ksm_partial(const bf16* __restrict__ key,
                                                   float* __restrict__ part_m,
                                                   float* __restrict__ part_s) {
    int split = blockIdx.x, b = blockIdx.y;
    const int per = (Nc + KSM_NS - 1) / KSM_NS;  // 67
    int n0 = split * per, n1 = min(Nc, n0 + per);
    int c4 = threadIdx.x * 4;
    const unsigned short* kp = (const unsigned short*)(key + (long)b * Nc * Dc) + c4;
    float m[4] = {-3.0e38f, -3.0e38f, -3.0e38f, -3.0e38f};
    float s[4] = {0.f, 0.f, 0.f, 0.f};
    for (int n = n0; n < n1; ++n) {
        ushort4 raw = *(const ushort4*)(kp + (long)n * Dc);
        unsigned short rr[4] = {raw.x, raw.y, raw.z, raw.w};
        #pragma unroll
        for (int j = 0; j < 4; ++j) {
            float v = us2f(rr[j]);
            if (v <= m[j]) {
                s[j] += __expf(v - m[j]);
            } else {
                s[j] = s[j] * __expf(m[j] - v) + 1.f;
                m[j] = v;
            }
        }
    }
    long off = ((long)split * Bc + b) * Dc + c4;
    #pragma unroll
    for (int j = 0; j < 4; ++j) { part_m[off + j] = m[j]; part_s[off + j] = s[j]; }
}

// pass 2: combine split partials -> per-column (max, 1/sum)
__global__ __launch_bounds__(256) void ksm_reduce(const float* __restrict__ part_m,
                                                  const float* __restrict__ part_s,
                                                  float* __restrict__ cs_m,
                                                  float* __restrict__ cs_inv) {
    int idx = blockIdx.x * 256 + threadIdx.x;
    float gm = -3.0e38f;
    #pragma unroll 8
    for (int sp = 0; sp < KSM_NS; ++sp)
        gm = fmaxf(gm, part_m[(long)sp * Bc * Dc + idx]);
    float s = 0.f;
    #pragma unroll 8
    for (int sp = 0; sp < KSM_NS; ++sp)
        s += part_s[(long)sp * Bc * Dc + idx] * __expf(part_m[(long)sp * Bc * Dc + idx] - gm);
    cs_m[idx] = gm;
    cs_inv[idx] = 1.f / s;
}

// att[bh][d][l] += sum_{n in split} exp(k[b,n,h*128+d]-m_d) * v[b,n,h*128+l]
// (atomic accumulation; att pre-zeroed via hipMemsetAsync)
constexpr int ATT_SPLIT = 16;
__global__ __launch_bounds__(256) void att_kernel(const bf16* __restrict__ key,
                                                  const bf16* __restrict__ v,
                                                  const float* __restrict__ cs_m,
                                                  float* __restrict__ att) {
    int bh = blockIdx.x;
    int b = bh >> 3, h = bh & 7;
    int split = blockIdx.y;
    const bf16* kb = key + (long)b * Nc * Dc + h * 128;
    const bf16* vb = v + (long)b * Nc * Dc + h * 128;
    float* ap = att + (long)bh * 16384;
    const int per = (Nc + ATT_SPLIT - 1) / ATT_SPLIT;  // 133
    int n0 = split * per, n1 = min(Nc, n0 + per);
    __shared__ float ks[16][128], vs[16][128];
    __shared__ float ms[128];
    int tid = threadIdx.x, tx = tid & 15, ty = tid >> 4;
    if (tid < 128) ms[tid] = cs_m[b * Dc + h * 128 + tid];
    __syncthreads();
    float acc[8][8] = {};
    for (int nb = n0; nb < n1; nb += 16) {
        int nc = min(16, n1 - nb);
        for (int e = tid; e < 2048; e += 256) {
            int nn = e >> 7, d = e & 127;
            float kvv = 0.f, vvv = 0.f;
            if (nn < nc) {
                long off = (long)(nb + nn) * Dc + d;
                kvv = __expf(b2f(kb[off]) - ms[d]);
                vvv = b2f(vb[off]);
            }
            ks[nn][d] = kvv; vs[nn][d] = vvv;
        }
        __syncthreads();
        #pragma unroll
        for (int nn = 0; nn < 16; ++nn) {
            float kr[8], vr[8];
            #pragma unroll
            for (int i = 0; i < 8; ++i) kr[i] = ks[nn][ty * 8 + i];
            #pragma unroll
            for (int j = 0; j < 8; ++j) vr[j] = vs[nn][tx * 8 + j];
            #pragma unroll
            for (int i = 0; i < 8; ++i)
                #pragma unroll
                for (int j = 0; j < 8; ++j)
                    acc[i][j] = fmaf(kr[i], vr[j], acc[i][j]);
        }
        __syncthreads();
    }
    for (int i = 0; i < 8; ++i)
        for (int j = 0; j < 8; ++j)
            atomicAdd(&ap[(ty * 8 + i) * 128 + tx * 8 + j], acc[i][j]);
}

// y[b,t,h*128+l] = sum_d q[b,t,h*128+d] * (att[bh][d][l] * cs_inv[b,h*128+d])
__global__ __launch_bounds__(256) void y_kernel(const bf16* __restrict__ q,
                                                const float* __restrict__ att,
                                                const float* __restrict__ cs_inv,
                                                bf16* __restrict__ y) {
    int bh = blockIdx.y;
    int b = bh >> 3, h = bh & 7;
    const bf16* qb = q + (long)b * Tc * Dc + h * 128;
    const float* ab = att + (long)bh * 16384;
    const float* ivb = cs_inv + b * Dc + h * 128;
    bf16* yb = y + (long)b * Tc * Dc + h * 128;
    int t0 = blockIdx.x * 64;
    __shared__ float qs[16][68];
    __shared__ float as[16][128];
    int tid = threadIdx.x, tx = tid & 15, ty = tid >> 4;
    float acc[4][8] = {};
    for (int k0 = 0; k0 < 128; k0 += 16) {
        for (int e = tid; e < 1024; e += 256) {
            int m = e >> 4, k = e & 15;
            qs[k][m] = b2f(qb[(long)(t0 + m) * Dc + k0 + k]);
        }
        for (int e = tid; e < 2048; e += 256) {
            int k = e >> 7, n = e & 127;
            as[k][n] = ab[(k0 + k) * 128 + n] * ivb[k0 + k];
        }
        __syncthreads();
        #pragma unroll
        for (int k = 0; k < 16; ++k) {
            float a[4], w[8];
            #pragma unroll
            for (int i = 0; i < 4; ++i) a[i] = qs[k][ty * 4 + i];
            #pragma unroll
            for (int j = 0; j < 8; ++j) w[j] = as[k][tx * 8 + j];
            #pragma unroll
            for (int i = 0; i < 4; ++i)
                #pragma unroll
                for (int j = 0; j < 8; ++j)
                    acc[i][j] = fmaf(a[i], w[j], acc[i][j]);
        }
        __syncthreads();
    }
    for (int i = 0; i < 4; ++i)
        for (int j = 0; j < 8; ++j)
            yb[(long)(t0 + ty * 4 + i) * Dc + tx * 8 + j] = f2b(acc[i][j]);
}

// s = silu( LN(y)*(1+scale) + shift )
__global__ __launch_bounds__(256) void film_kernel(const bf16* __restrict__ y,
                                                   const float* __restrict__ eo,
                                                   const float* __restrict__ g,
                                                   const float* __restrict__ bta,
                                                   bf16* __restrict__ s) {
    long row = blockIdx.x;
    int b = (int)(row >> 10);
    const bf16* yr = y + row * Dc;
    float sum = 0.f, sum2 = 0.f;
    for (int c = threadIdx.x; c < Dc; c += 256) { float v = b2f(yr[c]); sum += v; sum2 += v * v; }
    float2 r = block_sum2(sum, sum2);
    float mean = r.x / Dc;
    float var = r.y / Dc - mean * mean;
    float inv = rsqrtf(var + 1e-5f);
    const float* sc = eo + (long)b * 2048;
    const float* sf = sc + 1024;
    bf16* so = s + row * Dc;
    for (int c = threadIdx.x; c < Dc; c += 256) {
        float v = (b2f(yr[c]) - mean) * inv * g[c] + bta[c];
        v = v * (1.f + sc[c]) + sf[c];
        so[c] = f2b(v / (1.f + expf(-v)));
    }
}

extern "C" void kernel_launch(void* const* d_in, const int* in_sizes, int n_in,
                              void* d_out, int out_size, void* d_ws, size_t ws_size,
                              hipStream_t stream) {
    if (ws_size < WS_NEED) return;

    const float* x         = (const float*)d_in[0];
    const float* xf        = (const float*)d_in[1];
    const float* emb       = (const float*)d_in[2];
    const float* src_mask  = (const float*)d_in[3];
    const int*   cond_type = (const int*)d_in[4];
    const float* re_motion = (const float*)d_in[5];
    const float* re_text   = (const float*)d_in[6];
    const float* re_mask   = (const float*)d_in[7];
    const float* ln_g  = (const float*)d_in[8];
    const float* ln_b  = (const float*)d_in[9];
    const float* tln_g = (const float*)d_in[10];
    const float* tln_b = (const float*)d_in[11];
    const float* rn1_g = (const float*)d_in[12];
    const float* rn1_b = (const float*)d_in[13];
    const float* rn2_g = (const float*)d_in[14];
    const float* rn2_b = (const float*)d_in[15];
    const float* Wq  = (const float*)d_in[16];
    const float* bq  = (const float*)d_in[17];
    const float* Wkt = (const float*)d_in[18];
    const float* bkt = (const float*)d_in[19];
    const float* Wvt = (const float*)d_in[20];
    const float* bvt = (const float*)d_in[21];
    const float* Wkm = (const float*)d_in[22];
    const float* bkm = (const float*)d_in[23];
    const float* Wvm = (const float*)d_in[24];
    const float* bvm = (const float*)d_in[25];
    const float* Wkr = (const float*)d_in[26];
    const float* bkr = (const float*)d_in[27];
    const float* Wvr = (const float*)d_in[28];
    const float* bvr = (const float*)d_in[29];
    const float* We  = (const float*)d_in[30];
    const float* be  = (const float*)d_in[31];
    const float* sln_g = (const float*)d_in[32];
    const float* sln_b = (const float*)d_in[33];
    const float* Wo  = (const float*)d_in[34];
    const float* bo  = (const float*)d_in[35];

    float* ws = (float*)d_ws;
    float* stats1   = ws + F_STATS1;
    float* stats2   = ws + F_STATS2;
    float* key_add  = ws + F_KEYADD;
    float* val_mul  = ws + F_VALMUL;
    float* cs_m     = ws + F_SILU;
    float* cs_inv   = cs_m + Bc * Dc;
    float* eo       = ws + F_EO;
    float* att      = ws + F_ATT;
    bf16* wb = (bf16*)(ws + F_END);
    bf16* norm_x16 = wb + B_NORMX;
    bf16* q16      = wb + B_Q;
    bf16* key16    = wb + B_KEY;
    bf16* v16      = wb + B_V;
    bf16* nxf16    = wb + B_NXF;
    short* WtQ  = (short*)(wb + B_WQ);   // WQ|WKM|WVM contiguous -> [3072][1024]
    short* WtKM = (short*)(wb + B_WKM);
    short* WtVM = (short*)(wb + B_WVM);
    short* WtKT = (short*)(wb + B_WKT);  // WKT|WVT contiguous -> [2048][768]
    short* WtVT = (short*)(wb + B_WVT);
    short* WtKR = (short*)(wb + B_WKR);
    short* WtVR = (short*)(wb + B_WVR);
    short* WtO  = (short*)(wb + B_WO);
    bf16* y16 = wb + B_NORMX;            // norm_x dead after QKV gemm
    bf16* s16 = q16;                     // q dead after y_kernel
    float* eo_part = (float*)(wb + B_V); // v16 dead after att_kernel
    float* part_m = (float*)(wb + B_WKR);
    float* part_s = part_m + (long)KSM_NS * Bc * Dc;

    float* out = (float*)d_out;
    const long sKey = (long)Nc * Dc;

    // 1. LayerNorms + stats
    ln_rows<bf16><<<dim3(Bc * Tc), dim3(256), 0, stream>>>(x, ln_g, ln_b, norm_x16, Dc);
    ln_rows<bf16><<<dim3(Bc * NTc), dim3(256), 0, stream>>>(xf, tln_g, tln_b, nxf16, LTc);
    ln_stats_both<<<dim3(Bc * KRc), dim3(256), 0, stream>>>(re_motion, re_text, stats1, stats2);

    // 2. Masks
    prep_masks<<<dim3((Bc * Nc + 255) / 256), dim3(256), 0, stream>>>(
        cond_type, src_mask, re_mask, key_add, val_mul);

    // 3. Weight transposes
    transpose_w<<<dim3(32, 32), dim3(256), 0, stream>>>(Wq, WtQ, 1024, 1024);
    transpose_w<<<dim3(32, 32), dim3(256), 0, stream>>>(Wkm, WtKM, 1024, 1024);
    transpose_w<<<dim3(32, 32), dim3(256), 0, stream>>>(Wvm, WtVM, 1024, 1024);
    transpose_w<<<dim3(32, 24), dim3(256), 0, stream>>>(Wkt, WtKT, 768, 1024);
    transpose_w<<<dim3(32, 24), dim3(256), 0, stream>>>(Wvt, WtVT, 768, 1024);
    transpose_w<<<dim3(32, 64), dim3(256), 0, stream>>>(Wkr, WtKR, 2048, 1024);
    transpose_w<<<dim3(32, 32), dim3(256), 0, stream>>>(Wvr, WtVR, 1024, 1024);
    transpose_w<<<dim3(32, 32), dim3(256), 0, stream>>>(Wo, WtO, 1024, 1024);

    // 4. MFMA GEMMs
    // Fused {query, key_motion, value_motion}: 1536 blocks
    gemm_bt_qkv<<<dim3(24, 8, Bc), dim3(256), 0, stream>>>(
        (const short*)norm_x16, Dc, (long)Tc * Dc, WtQ, 1024,
        bq, bkm, bvm, key_add + NTc + KRc, val_mul + NTc + KRc,
        q16, (long)Tc * Dc,
        key16 + (long)(NTc + KRc) * Dc, sKey,
        v16 + (long)(NTc + KRc) * Dc, sKey,
        8, Tc, 1024);
    // Fused {key_text, value_text}
    gemm_bt_qkv<<<dim3(16, 1, Bc), dim3(256), 0, stream>>>(
        (const short*)nxf16, LTc, (long)NTc * LTc, WtKT, 768,
        nullptr, bkt, bvt, key_add, val_mul,
        nullptr, 0, key16, sKey, v16, sKey,
        0, NTc, 768);
    // key_retr (LN fused, K=2048)
    gemm_lnA_mfma<bf16><<<dim3(8, 8, Bc), dim3(256), 0, stream>>>(
        re_motion, re_text, stats1, rn1_g, rn1_b, WtKR, 2048, bkr,
        key_add + NTc, Nc, nullptr, 0, key16 + (long)NTc * Dc, Dc, sKey, 2048);
    // value_retr (LN fused, K=1024)
    gemm_lnA_mfma<bf16><<<dim3(8, 8, Bc), dim3(256), 0, stream>>>(
        re_motion, nullptr, stats2, rn2_g, rn2_b, WtVR, 1024, bvr,
        nullptr, 0, val_mul + NTc, Nc, v16 + (long)NTc * Dc, Dc, sKey, 1024);

    // 5. Softmaxes: q in place; key via column stats only
    softmax_head<<<dim3(Bc * Tc * Hc / 4), dim3(256), 0, stream>>>(q16);
    ksm_partial<<<dim3(KSM_NS, Bc), dim3(256), 0, stream>>>(key16, part_m, part_s);
    ksm_reduce<<<dim3(32), dim3(256), 0, stream>>>(part_m, part_s, cs_m, cs_inv);

    // 6. att = p^T v, atomic split-N accumulation (att zeroed first)
    hipMemsetAsync(att, 0, (size_t)Bc * Hc * 128 * 128 * sizeof(float), stream);
    att_kernel<<<dim3(Bc * Hc, ATT_SPLIT), dim3(256), 0, stream>>>(key16, v16, cs_m, att);

    // 7. y = q @ (att * inv)
    y_kernel<<<dim3(Tc / 64, Bc * Hc), dim3(256), 0, stream>>>(q16, att, cs_inv, y16);

    // 8. eo = silu(emb) @ We + be
    eo_partial<<<dim3(8, 32), dim3(256), 0, stream>>>(emb, We, eo_part);
    eo_reduce<<<dim3(64), dim3(256), 0, stream>>>(eo_part, be, eo);

    // 9. FiLM + silu
    film_kernel<<<dim3(Bc * Tc), dim3(256), 0, stream>>>(y16, eo, sln_g, sln_b, s16);

    // 10. out = x + s @ Wo + bo
    gemm_bt<float><<<dim3(8, 64, 1), dim3(256), 0, stream>>>(
        (const short*)s16, Dc, 0, WtO, 1024, bo,
        x, Dc, 0, out, Dc, 0, Bc * Tc, 1024);
}